// Round 2
// baseline (1615.090 us; speedup 1.0000x reference)
//
#include <hip/hip_runtime.h>

// Problem: 2-layer GCN encoder + 2 MLP decoders.
//   N = 100000, E = 1600000, NFEAT = 128, NHID = 64, DEC_HID = 128
// Outputs: h [N,64] | x_hat [N,128] | m_hat [N,128], fp32, concatenated in d_out.

// ---------------- degree / norm ----------------

__global__ void degree_kernel(const int* __restrict__ dst, float* __restrict__ cnt, int E) {
    int e = blockIdx.x * blockDim.x + threadIdx.x;
    if (e < E) atomicAdd(&cnt[dst[e]], 1.0f);
}

__global__ void dinv_kernel(const float* __restrict__ cnt, float* __restrict__ dinv, int N) {
    int i = blockIdx.x * blockDim.x + threadIdx.x;
    if (i < N) dinv[i] = rsqrtf(cnt[i] + 1.0f);
}

// ---------------- GEMM: out[N,64] = A[N,K] @ W[K,64] ----------------
// block 256 = 4 row-groups x 64 cols; 32 rows/block, R=8 rows per thread.
template <int K>
__global__ __launch_bounds__(256) void gemm64(const float* __restrict__ A,
                                              const float* __restrict__ W,
                                              float* __restrict__ out, int N) {
    constexpr int R = 8;
    const int j  = threadIdx.x & 63;
    const int rg = threadIdx.x >> 6;   // 0..3
    const int row0 = blockIdx.x * 32;
    __shared__ float As[32][K];
    for (int idx = threadIdx.x; idx < 32 * K; idx += 256) {
        int r = idx / K, k = idx - r * K;
        int row = row0 + r;
        As[r][k] = (row < N) ? A[(long long)row * K + k] : 0.0f;
    }
    __syncthreads();
    float acc[R];
#pragma unroll
    for (int r = 0; r < R; ++r) acc[r] = 0.0f;
    for (int k = 0; k < K; ++k) {
        float w = W[k * 64 + j];
#pragma unroll
        for (int r = 0; r < R; ++r) acc[r] += As[rg * R + r][k] * w;
    }
#pragma unroll
    for (int r = 0; r < R; ++r) {
        int row = row0 + rg * R + r;
        if (row < N) out[(long long)row * 64 + j] = acc[r];
    }
}

// ---------------- seed accumulator with self-loop term: acc = m * dinv^2 ----------------
__global__ void selfseed_kernel(const float* __restrict__ m, const float* __restrict__ dinv,
                                float* __restrict__ acc, long long total) {
    long long idx = (long long)blockIdx.x * blockDim.x + threadIdx.x;
    if (idx >= total) return;
    int i = (int)(idx >> 6);
    float dv = dinv[i];
    acc[idx] = m[idx] * (dv * dv);
}

// ---------------- edge scatter: acc[dst] += m[src] * (enorm?) ----------------
// one wave (64 lanes) per edge, lane = feature. NORM: multiply by dinv[s]*dinv[d].
template <int NORM>
__global__ __launch_bounds__(256) void scatter64(const float* __restrict__ m,
                                                 const int* __restrict__ src,
                                                 const int* __restrict__ dst,
                                                 const float* __restrict__ dinv,
                                                 float* __restrict__ acc, int E) {
    long long gid = (long long)blockIdx.x * blockDim.x + threadIdx.x;
    int e = (int)(gid >> 6);
    if (e >= E) return;
    int j = (int)(gid & 63);
    int s = src[e], d = dst[e];
    float v = m[(long long)s * 64 + j];
    if (NORM) v *= dinv[s] * dinv[d];
    atomicAdd(&acc[(long long)d * 64 + j], v);
}

// ---------------- in-place ReLU ----------------
__global__ void relu_kernel(float* __restrict__ a, long long total) {
    long long idx = (long long)blockIdx.x * blockDim.x + threadIdx.x;
    if (idx < total) a[idx] = fmaxf(a[idx], 0.0f);
}

// ---------------- in-place divide by max(cnt,1): neighbor mean ----------------
__global__ void meandiv_kernel(float* __restrict__ a, const float* __restrict__ cnt,
                               long long total) {
    long long idx = (long long)blockIdx.x * blockDim.x + threadIdx.x;
    if (idx >= total) return;
    int i = (int)(idx >> 6);
    a[idx] *= (1.0f / fmaxf(cnt[i], 1.0f));
}

// ---------------- fused 2-layer MLP: out = relu(In@Wa + ba) @ Wb + bb ----------------
// In: [N,64], Wa: [64,128], Wb: [128,128]. Block 128 threads, R=16 rows/block.
__global__ __launch_bounds__(128) void mlp2_kernel(const float* __restrict__ In,
                                                   const float* __restrict__ Wa,
                                                   const float* __restrict__ ba,
                                                   const float* __restrict__ Wb,
                                                   const float* __restrict__ bb,
                                                   float* __restrict__ out, int N) {
    constexpr int R = 16;
    const int j = threadIdx.x;          // 0..127 (output col)
    const int row0 = blockIdx.x * R;
    __shared__ float ins[R][64];
    __shared__ float t[R][128];
    for (int idx = threadIdx.x; idx < R * 64; idx += 128) {
        int r = idx >> 6, k = idx & 63;
        int row = row0 + r;
        ins[r][k] = (row < N) ? In[(long long)row * 64 + k] : 0.0f;
    }
    __syncthreads();
    float acc[R];
    float b1 = ba[j];
#pragma unroll
    for (int r = 0; r < R; ++r) acc[r] = b1;
    for (int k = 0; k < 64; ++k) {
        float w = Wa[k * 128 + j];
#pragma unroll
        for (int r = 0; r < R; ++r) acc[r] += ins[r][k] * w;
    }
#pragma unroll
    for (int r = 0; r < R; ++r) t[r][j] = fmaxf(acc[r], 0.0f);
    __syncthreads();
    float b2 = bb[j];
#pragma unroll
    for (int r = 0; r < R; ++r) acc[r] = b2;
    for (int k = 0; k < 128; ++k) {
        float w = Wb[k * 128 + j];
#pragma unroll
        for (int r = 0; r < R; ++r) acc[r] += t[r][k] * w;
    }
#pragma unroll
    for (int r = 0; r < R; ++r) {
        int row = row0 + r;
        if (row < N) out[(long long)row * 128 + j] = acc[r];
    }
}

extern "C" void kernel_launch(void* const* d_in, const int* in_sizes, int n_in,
                              void* d_out, int out_size, void* d_ws, size_t ws_size,
                              hipStream_t stream) {
    const float* x   = (const float*)d_in[0];
    const int*   ei  = (const int*)  d_in[1];
    const float* W1  = (const float*)d_in[2];
    const float* W2  = (const float*)d_in[3];
    const float* Wx1 = (const float*)d_in[4];
    const float* bx1 = (const float*)d_in[5];
    const float* Wx2 = (const float*)d_in[6];
    const float* bx2 = (const float*)d_in[7];
    const float* Wh1 = (const float*)d_in[8];
    const float* bh1 = (const float*)d_in[9];
    const float* Wh2 = (const float*)d_in[10];
    const float* bh2 = (const float*)d_in[11];

    const int NFEAT = 128, NHID = 64;
    const int N = in_sizes[0] / NFEAT;       // 100000
    const int E = in_sizes[1] / 2;           // 1600000

    float* out   = (float*)d_out;
    float* h_out = out;                          // [N,64]
    float* xhat  = out + (long long)N * NHID;    // [N,128]
    float* mhat  = xhat + (long long)N * NFEAT;  // [N,128]

    // workspace layout (floats): cnt[N] | dinv[N] | mbuf[N*64] | hbuf[N*64]
    // total = 130*N floats ~= 52 MB
    float* ws   = (float*)d_ws;
    float* cnt  = ws;
    float* dinv = ws + N;
    float* mbuf = ws + 2LL * N;
    float* hbuf = ws + 2LL * N + 64LL * N;

    const long long n64 = (long long)N * 64;
    const int B = 256;
    const int gridE   = (E + B - 1) / B;
    const int gridN   = (N + B - 1) / B;
    const int gridE64 = (int)(((long long)E * 64 + B - 1) / B);
    const int gridN64 = (int)((n64 + B - 1) / B);
    const int gridG   = (N + 31) / 32;       // gemm64 blocks
    const int gridMLP = (N + 15) / 16;       // mlp2 blocks

    const int* srcp = ei;
    const int* dstp = ei + E;

    // degree + norm
    hipMemsetAsync(cnt, 0, (size_t)N * sizeof(float), stream);
    degree_kernel<<<gridE, B, 0, stream>>>(dstp, cnt, E);
    dinv_kernel<<<gridN, B, 0, stream>>>(cnt, dinv, N);

    // layer 1: m = x@W1 ; hbuf = m*dinv^2 ; scatter-atomics on top ; relu in place
    gemm64<128><<<gridG, B, 0, stream>>>(x, W1, mbuf, N);
    selfseed_kernel<<<gridN64, B, 0, stream>>>(mbuf, dinv, hbuf, n64);
    scatter64<1><<<gridE64, B, 0, stream>>>(mbuf, srcp, dstp, dinv, hbuf, E);
    relu_kernel<<<gridN64, B, 0, stream>>>(hbuf, n64);

    // layer 2: m = hbuf@W2 ; h_out = m*dinv^2 ; scatter-atomics on top (no relu)
    gemm64<64><<<gridG, B, 0, stream>>>(hbuf, W2, mbuf, N);
    selfseed_kernel<<<gridN64, B, 0, stream>>>(mbuf, dinv, h_out, n64);
    scatter64<1><<<gridE64, B, 0, stream>>>(mbuf, srcp, dstp, dinv, h_out, E);

    // neighbor mean: hbuf = scatter(h_out) / max(cnt,1)
    hipMemsetAsync(hbuf, 0, (size_t)n64 * sizeof(float), stream);
    scatter64<0><<<gridE64, B, 0, stream>>>(h_out, srcp, dstp, dinv, hbuf, E);
    meandiv_kernel<<<gridN64, B, 0, stream>>>(hbuf, cnt, n64);

    // decoders
    mlp2_kernel<<<gridMLP, 128, 0, stream>>>(h_out, Wx1, bx1, Wx2, bx2, xhat, N);
    mlp2_kernel<<<gridMLP, 128, 0, stream>>>(hbuf, Wh1, bh1, Wh2, bh2, mhat, N);
}

// Round 3
// 1131.416 us; speedup vs baseline: 1.4275x; 1.4275x over previous
//
#include <hip/hip_runtime.h>

// 2-layer GCN encoder + 2 MLP decoders.
//   N = 100000, E = 1600000, NFEAT = 128, NHID = 64, DEC_HID = 128
// Outputs: h [N,64] | x_hat [N,128] | m_hat [N,128], fp32, concatenated in d_out.
//
// R3: CSR-by-dst built on device each call; aggregation is atomic-free gather
// (one wave per dst row, 64 lanes = features). R2 counters showed scatter64
// atomic-bound: 400 MB WRITE_SIZE/pass (4B fabric write per atomicAdd).

// ---------------- CSR build ----------------

__global__ void zero_int_kernel(int* __restrict__ p, int n) {
    int i = blockIdx.x * blockDim.x + threadIdx.x;
    if (i < n) p[i] = 0;
}

__global__ void degree_kernel(const int* __restrict__ dst, int* __restrict__ deg, int E) {
    int e = blockIdx.x * blockDim.x + threadIdx.x;
    if (e < E) atomicAdd(&deg[dst[e]], 1);
}

// single-block exclusive scan: rowStart[0..N] (rowStart[N] = E), cursor = copy.
__global__ __launch_bounds__(1024) void scan_kernel(const int* __restrict__ deg,
                                                    int* __restrict__ rowStart,
                                                    int* __restrict__ cursor, int N) {
    __shared__ int sdata[1024];
    const int t = threadIdx.x;
    const int seg = (N + 1023) / 1024;
    const int lo = t * seg;
    const int hi = min(lo + seg, N);
    int mysum = 0;
    for (int i = lo; i < hi; ++i) mysum += deg[i];
    sdata[t] = mysum;
    __syncthreads();
    // Hillis-Steele inclusive scan
    for (int off = 1; off < 1024; off <<= 1) {
        int v = (t >= off) ? sdata[t - off] : 0;
        __syncthreads();
        sdata[t] += v;
        __syncthreads();
    }
    int running = sdata[t] - mysum;   // exclusive prefix of this segment
    for (int i = lo; i < hi; ++i) {
        rowStart[i] = running;
        cursor[i]   = running;
        running += deg[i];
    }
    if (t == 1023) rowStart[N] = running;   // == E
}

__global__ void fill_kernel(const int* __restrict__ src, const int* __restrict__ dst,
                            int* __restrict__ cursor, int* __restrict__ adj, int E) {
    int e = blockIdx.x * blockDim.x + threadIdx.x;
    if (e >= E) return;
    int d = dst[e];
    int pos = atomicAdd(&cursor[d], 1);
    adj[pos] = src[e];
}

__global__ void dinv_kernel(const int* __restrict__ rowStart, float* __restrict__ dinv, int N) {
    int i = blockIdx.x * blockDim.x + threadIdx.x;
    if (i < N) {
        int deg = rowStart[i + 1] - rowStart[i];
        dinv[i] = rsqrtf((float)deg + 1.0f);
    }
}

// ---------------- GEMM: out[N,64] = A[N,K] @ W[K,64] ----------------
template <int K>
__global__ __launch_bounds__(256) void gemm64(const float* __restrict__ A,
                                              const float* __restrict__ W,
                                              float* __restrict__ out, int N) {
    constexpr int R = 8;
    const int j  = threadIdx.x & 63;
    const int rg = threadIdx.x >> 6;   // 0..3
    const int row0 = blockIdx.x * 32;
    __shared__ float As[32][K];
    for (int idx = threadIdx.x; idx < 32 * K; idx += 256) {
        int r = idx / K, k = idx - r * K;
        int row = row0 + r;
        As[r][k] = (row < N) ? A[(long long)row * K + k] : 0.0f;
    }
    __syncthreads();
    float acc[R];
#pragma unroll
    for (int r = 0; r < R; ++r) acc[r] = 0.0f;
    for (int k = 0; k < K; ++k) {
        float w = W[k * 64 + j];
#pragma unroll
        for (int r = 0; r < R; ++r) acc[r] += As[rg * R + r][k] * w;
    }
#pragma unroll
    for (int r = 0; r < R; ++r) {
        int row = row0 + rg * R + r;
        if (row < N) out[(long long)row * 64 + j] = acc[r];
    }
}

// ---------------- GCN aggregation by gather (atomic-free) ----------------
// one wave per dst row, lane = feature. out = dinv[d]*(m[d]*dinv[d] + sum m[s]*dinv[s])
template <int RELU>
__global__ __launch_bounds__(256) void gather_combine(const float* __restrict__ m,
                                                      const int* __restrict__ rowStart,
                                                      const int* __restrict__ adj,
                                                      const float* __restrict__ dinv,
                                                      float* __restrict__ out, int N) {
    long long gid = (long long)blockIdx.x * blockDim.x + threadIdx.x;
    int d = (int)(gid >> 6);
    if (d >= N) return;
    int j = (int)(gid & 63);
    int start = rowStart[d], end = rowStart[d + 1];
    float dv = dinv[d];
    float acc0 = m[(long long)d * 64 + j] * dv;
    float acc1 = 0.0f;
    int t = start;
    for (; t + 2 <= end; t += 2) {
        int s0 = adj[t], s1 = adj[t + 1];
        acc0 += m[(long long)s0 * 64 + j] * dinv[s0];
        acc1 += m[(long long)s1 * 64 + j] * dinv[s1];
    }
    if (t < end) {
        int s = adj[t];
        acc0 += m[(long long)s * 64 + j] * dinv[s];
    }
    float v = (acc0 + acc1) * dv;
    out[(long long)d * 64 + j] = RELU ? fmaxf(v, 0.0f) : v;
}

// neighbor mean: out = (sum_{s in N(d)} h[s]) / max(deg,1)
__global__ __launch_bounds__(256) void gather_mean(const float* __restrict__ h,
                                                   const int* __restrict__ rowStart,
                                                   const int* __restrict__ adj,
                                                   float* __restrict__ out, int N) {
    long long gid = (long long)blockIdx.x * blockDim.x + threadIdx.x;
    int d = (int)(gid >> 6);
    if (d >= N) return;
    int j = (int)(gid & 63);
    int start = rowStart[d], end = rowStart[d + 1];
    int deg = end - start;
    float acc0 = 0.0f, acc1 = 0.0f;
    int t = start;
    for (; t + 2 <= end; t += 2) {
        int s0 = adj[t], s1 = adj[t + 1];
        acc0 += h[(long long)s0 * 64 + j];
        acc1 += h[(long long)s1 * 64 + j];
    }
    if (t < end) acc0 += h[(long long)adj[t] * 64 + j];
    float inv = 1.0f / (float)max(deg, 1);
    out[(long long)d * 64 + j] = (acc0 + acc1) * inv;
}

// ---------------- fused 2-layer MLP: out = relu(In@Wa + ba) @ Wb + bb ----------------
__global__ __launch_bounds__(128) void mlp2_kernel(const float* __restrict__ In,
                                                   const float* __restrict__ Wa,
                                                   const float* __restrict__ ba,
                                                   const float* __restrict__ Wb,
                                                   const float* __restrict__ bb,
                                                   float* __restrict__ out, int N) {
    constexpr int R = 16;
    const int j = threadIdx.x;          // 0..127 (output col)
    const int row0 = blockIdx.x * R;
    __shared__ float ins[R][64];
    __shared__ float t[R][128];
    for (int idx = threadIdx.x; idx < R * 64; idx += 128) {
        int r = idx >> 6, k = idx & 63;
        int row = row0 + r;
        ins[r][k] = (row < N) ? In[(long long)row * 64 + k] : 0.0f;
    }
    __syncthreads();
    float acc[R];
    float b1 = ba[j];
#pragma unroll
    for (int r = 0; r < R; ++r) acc[r] = b1;
    for (int k = 0; k < 64; ++k) {
        float w = Wa[k * 128 + j];
#pragma unroll
        for (int r = 0; r < R; ++r) acc[r] += ins[r][k] * w;
    }
#pragma unroll
    for (int r = 0; r < R; ++r) t[r][j] = fmaxf(acc[r], 0.0f);
    __syncthreads();
    float b2 = bb[j];
#pragma unroll
    for (int r = 0; r < R; ++r) acc[r] = b2;
    for (int k = 0; k < 128; ++k) {
        float w = Wb[k * 128 + j];
#pragma unroll
        for (int r = 0; r < R; ++r) acc[r] += t[r][k] * w;
    }
#pragma unroll
    for (int r = 0; r < R; ++r) {
        int row = row0 + r;
        if (row < N) out[(long long)row * 128 + j] = acc[r];
    }
}

extern "C" void kernel_launch(void* const* d_in, const int* in_sizes, int n_in,
                              void* d_out, int out_size, void* d_ws, size_t ws_size,
                              hipStream_t stream) {
    const float* x   = (const float*)d_in[0];
    const int*   ei  = (const int*)  d_in[1];
    const float* W1  = (const float*)d_in[2];
    const float* W2  = (const float*)d_in[3];
    const float* Wx1 = (const float*)d_in[4];
    const float* bx1 = (const float*)d_in[5];
    const float* Wx2 = (const float*)d_in[6];
    const float* bx2 = (const float*)d_in[7];
    const float* Wh1 = (const float*)d_in[8];
    const float* bh1 = (const float*)d_in[9];
    const float* Wh2 = (const float*)d_in[10];
    const float* bh2 = (const float*)d_in[11];

    const int NFEAT = 128, NHID = 64;
    const int N = in_sizes[0] / NFEAT;       // 100000
    const int E = in_sizes[1] / 2;           // 1600000

    float* out   = (float*)d_out;
    float* h_out = out;                          // [N,64]
    float* xhat  = out + (long long)N * NHID;    // [N,128]
    float* mhat  = xhat + (long long)N * NFEAT;  // [N,128]

    // workspace layout:
    //   ints:  deg[N] | rowStart[N+1] | cursor[N] | adj[E]
    //   float: dinv[N] | mbuf[N*64] | hbuf[N*64]
    char* wsb = (char*)d_ws;
    int*   deg      = (int*)wsb;                         wsb += (size_t)N * 4;
    int*   rowStart = (int*)wsb;                         wsb += (size_t)(N + 1) * 4;
    int*   cursor   = (int*)wsb;                         wsb += (size_t)N * 4;
    int*   adj      = (int*)wsb;                         wsb += (size_t)E * 4;
    float* dinv     = (float*)wsb;                       wsb += (size_t)N * 4;
    float* mbuf     = (float*)wsb;                       wsb += (size_t)N * 64 * 4;
    float* hbuf     = (float*)wsb;

    const long long n64 = (long long)N * 64;
    const int B = 256;
    const int gridE   = (E + B - 1) / B;
    const int gridN   = (N + B - 1) / B;
    const int gridN64 = (int)((n64 + B - 1) / B);
    const int gridG   = (N + 31) / 32;       // gemm64 blocks
    const int gridMLP = (N + 15) / 16;       // mlp2 blocks

    const int* srcp = ei;
    const int* dstp = ei + E;

    // ---- CSR build ----
    zero_int_kernel<<<gridN, B, 0, stream>>>(deg, N);
    degree_kernel<<<gridE, B, 0, stream>>>(dstp, deg, E);
    scan_kernel<<<1, 1024, 0, stream>>>(deg, rowStart, cursor, N);
    fill_kernel<<<gridE, B, 0, stream>>>(srcp, dstp, cursor, adj, E);
    dinv_kernel<<<gridN, B, 0, stream>>>(rowStart, dinv, N);

    // ---- layer 1: m = x@W1 ; h1 = relu(gather_combine(m)) ----
    gemm64<128><<<gridG, B, 0, stream>>>(x, W1, mbuf, N);
    gather_combine<1><<<gridN64, B, 0, stream>>>(mbuf, rowStart, adj, dinv, hbuf, N);

    // ---- layer 2: m = h1@W2 ; h = gather_combine(m) -> d_out ----
    gemm64<64><<<gridG, B, 0, stream>>>(hbuf, W2, mbuf, N);
    gather_combine<0><<<gridN64, B, 0, stream>>>(mbuf, rowStart, adj, dinv, h_out, N);

    // ---- neighbor mean of h -> mbuf (reused) ----
    gather_mean<<<gridN64, B, 0, stream>>>(h_out, rowStart, adj, mbuf, N);

    // ---- decoders ----
    mlp2_kernel<<<gridMLP, 128, 0, stream>>>(h_out, Wx1, bx1, Wx2, bx2, xhat, N);
    mlp2_kernel<<<gridMLP, 128, 0, stream>>>(mbuf, Wh1, bh1, Wh2, bh2, mhat, N);
}

// Round 4
// 917.871 us; speedup vs baseline: 1.7596x; 1.2327x over previous
//
#include <hip/hip_runtime.h>

// 2-layer GCN encoder + 2 MLP decoders.
//   N = 100000, E = 1600000, NFEAT = 128, NHID = 64, DEC_HID = 128
// Outputs: h [N,64] | x_hat [N,128] | m_hat [N,128], fp32, concatenated in d_out.
//
// R3: CSR gather (atomic-free) replaced scatter atomics: 1615 -> 1131 us.
// R4: single-block scan (232 us, 0.15% occupancy) -> 3-phase hierarchical scan.

// ---------------- CSR build ----------------

__global__ void zero_int_kernel(int* __restrict__ p, int n) {
    int i = blockIdx.x * blockDim.x + threadIdx.x;
    if (i < n) p[i] = 0;
}

__global__ void degree_kernel(const int* __restrict__ dst, int* __restrict__ deg, int E) {
    int e = blockIdx.x * blockDim.x + threadIdx.x;
    if (e < E) atomicAdd(&deg[dst[e]], 1);
}

// ---- hierarchical exclusive scan over deg[N] -> rowStart[N+1], cursor[N] ----
// Each block covers 4096 elements (256 threads x 16 contiguous each).

__global__ __launch_bounds__(256) void scan_phase1(const int* __restrict__ deg,
                                                   int* __restrict__ blockSums, int N) {
    __shared__ int s[256];
    const int t = threadIdx.x;
    const int base = blockIdx.x * 4096 + t * 16;
    int sum = 0;
#pragma unroll
    for (int i = 0; i < 16; ++i) {
        int idx = base + i;
        sum += (idx < N) ? deg[idx] : 0;
    }
    s[t] = sum;
    __syncthreads();
    for (int off = 128; off > 0; off >>= 1) {
        if (t < off) s[t] += s[t + off];
        __syncthreads();
    }
    if (t == 0) blockSums[blockIdx.x] = s[0];
}

__global__ __launch_bounds__(256) void scan_phase2(int* __restrict__ blockSums,
                                                   int* __restrict__ rowStart,
                                                   int NB, int N) {
    __shared__ int s[256];
    const int t = threadIdx.x;
    int v = (t < NB) ? blockSums[t] : 0;
    s[t] = v;
    __syncthreads();
    for (int off = 1; off < 256; off <<= 1) {
        int u = (t >= off) ? s[t - off] : 0;
        __syncthreads();
        s[t] += u;
        __syncthreads();
    }
    if (t < NB) blockSums[t] = s[t] - v;      // exclusive block offsets
    if (t == 255) rowStart[N] = s[255];       // total == E
}

__global__ __launch_bounds__(256) void scan_phase3(const int* __restrict__ deg,
                                                   const int* __restrict__ blockOffs,
                                                   int* __restrict__ rowStart,
                                                   int* __restrict__ cursor, int N) {
    __shared__ int s[256];
    const int t = threadIdx.x;
    const int base = blockIdx.x * 4096 + t * 16;
    int local[16];
    int sum = 0;
#pragma unroll
    for (int i = 0; i < 16; ++i) {
        int idx = base + i;
        int v = (idx < N) ? deg[idx] : 0;
        local[i] = v;
        sum += v;
    }
    s[t] = sum;
    __syncthreads();
    for (int off = 1; off < 256; off <<= 1) {
        int u = (t >= off) ? s[t - off] : 0;
        __syncthreads();
        s[t] += u;
        __syncthreads();
    }
    int run = blockOffs[blockIdx.x] + s[t] - sum;   // exclusive prefix for this thread
#pragma unroll
    for (int i = 0; i < 16; ++i) {
        int idx = base + i;
        if (idx < N) {
            rowStart[idx] = run;
            cursor[idx]   = run;
            run += local[i];
        }
    }
}

__global__ void fill_kernel(const int* __restrict__ src, const int* __restrict__ dst,
                            int* __restrict__ cursor, int* __restrict__ adj, int E) {
    int e = blockIdx.x * blockDim.x + threadIdx.x;
    if (e >= E) return;
    int d = dst[e];
    int pos = atomicAdd(&cursor[d], 1);
    adj[pos] = src[e];
}

__global__ void dinv_kernel(const int* __restrict__ rowStart, float* __restrict__ dinv, int N) {
    int i = blockIdx.x * blockDim.x + threadIdx.x;
    if (i < N) {
        int deg = rowStart[i + 1] - rowStart[i];
        dinv[i] = rsqrtf((float)deg + 1.0f);
    }
}

// ---------------- GEMM: out[N,64] = A[N,K] @ W[K,64] ----------------
template <int K>
__global__ __launch_bounds__(256) void gemm64(const float* __restrict__ A,
                                              const float* __restrict__ W,
                                              float* __restrict__ out, int N) {
    constexpr int R = 8;
    const int j  = threadIdx.x & 63;
    const int rg = threadIdx.x >> 6;   // 0..3
    const int row0 = blockIdx.x * 32;
    __shared__ float As[32][K];
    for (int idx = threadIdx.x; idx < 32 * K; idx += 256) {
        int r = idx / K, k = idx - r * K;
        int row = row0 + r;
        As[r][k] = (row < N) ? A[(long long)row * K + k] : 0.0f;
    }
    __syncthreads();
    float acc[R];
#pragma unroll
    for (int r = 0; r < R; ++r) acc[r] = 0.0f;
    for (int k = 0; k < K; ++k) {
        float w = W[k * 64 + j];
#pragma unroll
        for (int r = 0; r < R; ++r) acc[r] += As[rg * R + r][k] * w;
    }
#pragma unroll
    for (int r = 0; r < R; ++r) {
        int row = row0 + rg * R + r;
        if (row < N) out[(long long)row * 64 + j] = acc[r];
    }
}

// ---------------- GCN aggregation by gather (atomic-free) ----------------
// one wave per dst row, lane = feature. out = dinv[d]*(m[d]*dinv[d] + sum m[s]*dinv[s])
template <int RELU>
__global__ __launch_bounds__(256) void gather_combine(const float* __restrict__ m,
                                                      const int* __restrict__ rowStart,
                                                      const int* __restrict__ adj,
                                                      const float* __restrict__ dinv,
                                                      float* __restrict__ out, int N) {
    long long gid = (long long)blockIdx.x * blockDim.x + threadIdx.x;
    int d = (int)(gid >> 6);
    if (d >= N) return;
    int j = (int)(gid & 63);
    int start = rowStart[d], end = rowStart[d + 1];
    float dv = dinv[d];
    float acc0 = m[(long long)d * 64 + j] * dv;
    float acc1 = 0.0f;
    int t = start;
    for (; t + 2 <= end; t += 2) {
        int s0 = adj[t], s1 = adj[t + 1];
        acc0 += m[(long long)s0 * 64 + j] * dinv[s0];
        acc1 += m[(long long)s1 * 64 + j] * dinv[s1];
    }
    if (t < end) {
        int s = adj[t];
        acc0 += m[(long long)s * 64 + j] * dinv[s];
    }
    float v = (acc0 + acc1) * dv;
    out[(long long)d * 64 + j] = RELU ? fmaxf(v, 0.0f) : v;
}

// neighbor mean: out = (sum_{s in N(d)} h[s]) / max(deg,1)
__global__ __launch_bounds__(256) void gather_mean(const float* __restrict__ h,
                                                   const int* __restrict__ rowStart,
                                                   const int* __restrict__ adj,
                                                   float* __restrict__ out, int N) {
    long long gid = (long long)blockIdx.x * blockDim.x + threadIdx.x;
    int d = (int)(gid >> 6);
    if (d >= N) return;
    int j = (int)(gid & 63);
    int start = rowStart[d], end = rowStart[d + 1];
    int deg = end - start;
    float acc0 = 0.0f, acc1 = 0.0f;
    int t = start;
    for (; t + 2 <= end; t += 2) {
        int s0 = adj[t], s1 = adj[t + 1];
        acc0 += h[(long long)s0 * 64 + j];
        acc1 += h[(long long)s1 * 64 + j];
    }
    if (t < end) acc0 += h[(long long)adj[t] * 64 + j];
    float inv = 1.0f / (float)max(deg, 1);
    out[(long long)d * 64 + j] = (acc0 + acc1) * inv;
}

// ---------------- fused 2-layer MLP: out = relu(In@Wa + ba) @ Wb + bb ----------------
__global__ __launch_bounds__(128) void mlp2_kernel(const float* __restrict__ In,
                                                   const float* __restrict__ Wa,
                                                   const float* __restrict__ ba,
                                                   const float* __restrict__ Wb,
                                                   const float* __restrict__ bb,
                                                   float* __restrict__ out, int N) {
    constexpr int R = 16;
    const int j = threadIdx.x;          // 0..127 (output col)
    const int row0 = blockIdx.x * R;
    __shared__ float ins[R][64];
    __shared__ float t[R][128];
    for (int idx = threadIdx.x; idx < R * 64; idx += 128) {
        int r = idx >> 6, k = idx & 63;
        int row = row0 + r;
        ins[r][k] = (row < N) ? In[(long long)row * 64 + k] : 0.0f;
    }
    __syncthreads();
    float acc[R];
    float b1 = ba[j];
#pragma unroll
    for (int r = 0; r < R; ++r) acc[r] = b1;
    for (int k = 0; k < 64; ++k) {
        float w = Wa[k * 128 + j];
#pragma unroll
        for (int r = 0; r < R; ++r) acc[r] += ins[r][k] * w;
    }
#pragma unroll
    for (int r = 0; r < R; ++r) t[r][j] = fmaxf(acc[r], 0.0f);
    __syncthreads();
    float b2 = bb[j];
#pragma unroll
    for (int r = 0; r < R; ++r) acc[r] = b2;
    for (int k = 0; k < 128; ++k) {
        float w = Wb[k * 128 + j];
#pragma unroll
        for (int r = 0; r < R; ++r) acc[r] += t[r][k] * w;
    }
#pragma unroll
    for (int r = 0; r < R; ++r) {
        int row = row0 + r;
        if (row < N) out[(long long)row * 128 + j] = acc[r];
    }
}

extern "C" void kernel_launch(void* const* d_in, const int* in_sizes, int n_in,
                              void* d_out, int out_size, void* d_ws, size_t ws_size,
                              hipStream_t stream) {
    const float* x   = (const float*)d_in[0];
    const int*   ei  = (const int*)  d_in[1];
    const float* W1  = (const float*)d_in[2];
    const float* W2  = (const float*)d_in[3];
    const float* Wx1 = (const float*)d_in[4];
    const float* bx1 = (const float*)d_in[5];
    const float* Wx2 = (const float*)d_in[6];
    const float* bx2 = (const float*)d_in[7];
    const float* Wh1 = (const float*)d_in[8];
    const float* bh1 = (const float*)d_in[9];
    const float* Wh2 = (const float*)d_in[10];
    const float* bh2 = (const float*)d_in[11];

    const int NFEAT = 128, NHID = 64;
    const int N = in_sizes[0] / NFEAT;       // 100000
    const int E = in_sizes[1] / 2;           // 1600000

    float* out   = (float*)d_out;
    float* h_out = out;                          // [N,64]
    float* xhat  = out + (long long)N * NHID;    // [N,128]
    float* mhat  = xhat + (long long)N * NFEAT;  // [N,128]

    // workspace layout:
    //   ints:  deg[N] | rowStart[N+1] | cursor[N] | adj[E] | blockSums[64]
    //   float: dinv[N] | mbuf[N*64] | hbuf[N*64]
    char* wsb = (char*)d_ws;
    int*   deg      = (int*)wsb;                         wsb += (size_t)N * 4;
    int*   rowStart = (int*)wsb;                         wsb += (size_t)(N + 1) * 4;
    int*   cursor   = (int*)wsb;                         wsb += (size_t)N * 4;
    int*   adj      = (int*)wsb;                         wsb += (size_t)E * 4;
    int*   blockSums= (int*)wsb;                         wsb += (size_t)64 * 4;
    float* dinv     = (float*)wsb;                       wsb += (size_t)N * 4;
    float* mbuf     = (float*)wsb;                       wsb += (size_t)N * 64 * 4;
    float* hbuf     = (float*)wsb;

    const long long n64 = (long long)N * 64;
    const int B = 256;
    const int gridE   = (E + B - 1) / B;
    const int gridN   = (N + B - 1) / B;
    const int gridN64 = (int)((n64 + B - 1) / B);
    const int gridG   = (N + 31) / 32;       // gemm64 blocks
    const int gridMLP = (N + 15) / 16;       // mlp2 blocks
    const int NB      = (N + 4095) / 4096;   // scan blocks (25 for N=100000)

    const int* srcp = ei;
    const int* dstp = ei + E;

    // ---- CSR build ----
    zero_int_kernel<<<gridN, B, 0, stream>>>(deg, N);
    degree_kernel<<<gridE, B, 0, stream>>>(dstp, deg, E);
    scan_phase1<<<NB, 256, 0, stream>>>(deg, blockSums, N);
    scan_phase2<<<1, 256, 0, stream>>>(blockSums, rowStart, NB, N);
    scan_phase3<<<NB, 256, 0, stream>>>(deg, blockSums, rowStart, cursor, N);
    fill_kernel<<<gridE, B, 0, stream>>>(srcp, dstp, cursor, adj, E);
    dinv_kernel<<<gridN, B, 0, stream>>>(rowStart, dinv, N);

    // ---- layer 1: m = x@W1 ; h1 = relu(gather_combine(m)) ----
    gemm64<128><<<gridG, B, 0, stream>>>(x, W1, mbuf, N);
    gather_combine<1><<<gridN64, B, 0, stream>>>(mbuf, rowStart, adj, dinv, hbuf, N);

    // ---- layer 2: m = h1@W2 ; h = gather_combine(m) -> d_out ----
    gemm64<64><<<gridG, B, 0, stream>>>(hbuf, W2, mbuf, N);
    gather_combine<0><<<gridN64, B, 0, stream>>>(mbuf, rowStart, adj, dinv, h_out, N);

    // ---- neighbor mean of h -> mbuf (reused) ----
    gather_mean<<<gridN64, B, 0, stream>>>(h_out, rowStart, adj, mbuf, N);

    // ---- decoders ----
    mlp2_kernel<<<gridMLP, 128, 0, stream>>>(h_out, Wx1, bx1, Wx2, bx2, xhat, N);
    mlp2_kernel<<<gridMLP, 128, 0, stream>>>(mbuf, Wh1, bh1, Wh2, bh2, mhat, N);
}

// Round 5
// 757.560 us; speedup vs baseline: 2.1320x; 1.2116x over previous
//
#include <hip/hip_runtime.h>

// 2-layer GCN encoder + 2 MLP decoders.
//   N = 100000, E = 1600000, NFEAT = 128, NHID = 64, DEC_HID = 128
// Outputs: h [N,64] | x_hat [N,128] | m_hat [N,128], fp32, concatenated in d_out.
//
// R3: CSR gather replaced scatter atomics: 1615 -> 1131 us.
// R4: hierarchical scan: 1131 -> 918 us. fill_kernel = 130 us, WRITE 105 MB (16x ampl.)
// R5: two-level LDS counting sort for CSR build (full-line writes); float4 gathers.

#define BUCK_SHIFT 7
#define BUCK_W 128
#define MAXB 1024
#define EMIT_CHUNK 8192

// ---------------- CSR build: two-level counting sort ----------------

// K1: per-bucket edge counts (LDS-aggregated histogram)
__global__ __launch_bounds__(256) void bucket_count(const int* __restrict__ dst,
                                                    int* __restrict__ bucketCnt,
                                                    int E, int NBUCK) {
    __shared__ int h[MAXB];
    for (int i = threadIdx.x; i < NBUCK; i += 256) h[i] = 0;
    __syncthreads();
    for (long long e = (long long)blockIdx.x * blockDim.x + threadIdx.x; e < E;
         e += (long long)gridDim.x * blockDim.x)
        atomicAdd(&h[dst[e] >> BUCK_SHIFT], 1);
    __syncthreads();
    for (int i = threadIdx.x; i < NBUCK; i += 256)
        if (h[i]) atomicAdd(&bucketCnt[i], h[i]);
}

// K2: exclusive scan of bucket counts (NBUCK <= 1024)
__global__ __launch_bounds__(1024) void bucket_scan(const int* __restrict__ cnt,
                                                    int* __restrict__ off,
                                                    int* __restrict__ cur,
                                                    int NBUCK, int E) {
    __shared__ int s[1024];
    const int t = threadIdx.x;
    int v = (t < NBUCK) ? cnt[t] : 0;
    s[t] = v;
    __syncthreads();
    for (int o = 1; o < 1024; o <<= 1) {
        int u = (t >= o) ? s[t - o] : 0;
        __syncthreads();
        s[t] += u;
        __syncthreads();
    }
    if (t < NBUCK) { off[t] = s[t] - v; cur[t] = s[t] - v; }
    if (t == 0) off[NBUCK] = E;
}

// K3: emit (src,dst) pairs into bucket-ordered staging with block-reserved runs
__global__ __launch_bounds__(256) void bucket_emit(const int* __restrict__ src,
                                                   const int* __restrict__ dst,
                                                   int* __restrict__ bucketCursor,
                                                   uint2* __restrict__ staging,
                                                   int E, int NBUCK) {
    __shared__ int h[MAXB];
    const int t = threadIdx.x;
    const long long base = (long long)blockIdx.x * EMIT_CHUNK;
    for (int i = t; i < NBUCK; i += 256) h[i] = 0;
    __syncthreads();
#pragma unroll
    for (int i = 0; i < EMIT_CHUNK / 256; ++i) {
        long long e = base + t + i * 256;
        if (e < E) atomicAdd(&h[dst[e] >> BUCK_SHIFT], 1);
    }
    __syncthreads();
    for (int i = t; i < NBUCK; i += 256) {
        int c = h[i];
        h[i] = c ? atomicAdd(&bucketCursor[i], c) : 0;
    }
    __syncthreads();
#pragma unroll
    for (int i = 0; i < EMIT_CHUNK / 256; ++i) {
        long long e = base + t + i * 256;
        if (e < E) {
            int d = dst[e];
            int pos = atomicAdd(&h[d >> BUCK_SHIFT], 1);
            staging[pos] = make_uint2((unsigned)src[e], (unsigned)d);
        }
    }
}

// K4: per-bucket counting sort -> rowStart + adj (one block per bucket)
__global__ __launch_bounds__(256) void bucket_sort(const uint2* __restrict__ staging,
                                                   const int* __restrict__ bucketOff,
                                                   int* __restrict__ rowStart,
                                                   int* __restrict__ adj,
                                                   int N, int NBUCK, int E) {
    __shared__ int h[BUCK_W];
    __shared__ int cur[BUCK_W];
    const int b = blockIdx.x;
    const int t = threadIdx.x;
    const int lo = b << BUCK_SHIFT;
    const int off = bucketOff[b];
    const int M = bucketOff[b + 1] - off;
    if (t < BUCK_W) h[t] = 0;
    __syncthreads();
    for (int i = t; i < M; i += 256)
        atomicAdd(&h[(int)staging[off + i].y - lo], 1);
    __syncthreads();
    if (t < BUCK_W) cur[t] = h[t];
    __syncthreads();
    for (int o = 1; o < BUCK_W; o <<= 1) {
        int u = 0;
        if (t < BUCK_W && t >= o) u = cur[t - o];
        __syncthreads();
        if (t < BUCK_W) cur[t] += u;
        __syncthreads();
    }
    if (t < BUCK_W) {
        int ex = off + cur[t] - h[t];     // exclusive prefix within bucket
        int d = lo + t;
        if (d < N) rowStart[d] = ex;
        cur[t] = ex;
    }
    if (b == 0 && t == 0) rowStart[N] = E;
    __syncthreads();
    for (int i = t; i < M; i += 256) {
        uint2 p = staging[off + i];
        int pos = atomicAdd(&cur[(int)p.y - lo], 1);
        adj[pos] = (int)p.x;
    }
}

__global__ void dinv_kernel(const int* __restrict__ rowStart, float* __restrict__ dinv, int N) {
    int i = blockIdx.x * blockDim.x + threadIdx.x;
    if (i < N) {
        int deg = rowStart[i + 1] - rowStart[i];
        dinv[i] = rsqrtf((float)deg + 1.0f);
    }
}

// ---------------- GEMM: out[N,64] = A[N,K] @ W[K,64] ----------------
template <int K>
__global__ __launch_bounds__(256) void gemm64(const float* __restrict__ A,
                                              const float* __restrict__ W,
                                              float* __restrict__ out, int N) {
    constexpr int R = 8;
    const int j  = threadIdx.x & 63;
    const int rg = threadIdx.x >> 6;   // 0..3
    const int row0 = blockIdx.x * 32;
    __shared__ float As[32][K];
    for (int idx = threadIdx.x; idx < 32 * K; idx += 256) {
        int r = idx / K, k = idx - r * K;
        int row = row0 + r;
        As[r][k] = (row < N) ? A[(long long)row * K + k] : 0.0f;
    }
    __syncthreads();
    float acc[R];
#pragma unroll
    for (int r = 0; r < R; ++r) acc[r] = 0.0f;
    for (int k = 0; k < K; ++k) {
        float w = W[k * 64 + j];
#pragma unroll
        for (int r = 0; r < R; ++r) acc[r] += As[rg * R + r][k] * w;
    }
#pragma unroll
    for (int r = 0; r < R; ++r) {
        int row = row0 + rg * R + r;
        if (row < N) out[(long long)row * 64 + j] = acc[r];
    }
}

// ---------------- GCN aggregation by gather, float4 lanes ----------------
// 16 lanes per dst row (lane l owns features 4l..4l+3).
// out = dinv[d]*(m[d]*dinv[d] + sum m[s]*dinv[s])
template <int RELU>
__global__ __launch_bounds__(256) void gather_combine4(const float4* __restrict__ m4,
                                                       const int* __restrict__ rowStart,
                                                       const int* __restrict__ adj,
                                                       const float* __restrict__ dinv,
                                                       float4* __restrict__ out4, int N) {
    int gid = blockIdx.x * 256 + threadIdx.x;
    int d = gid >> 4;
    if (d >= N) return;
    int l = gid & 15;
    int start = rowStart[d], end = rowStart[d + 1];
    float dv = dinv[d];
    float4 ms = m4[(long long)d * 16 + l];
    float4 a0, a1;
    a0.x = ms.x * dv; a0.y = ms.y * dv; a0.z = ms.z * dv; a0.w = ms.w * dv;
    a1.x = 0.f; a1.y = 0.f; a1.z = 0.f; a1.w = 0.f;
    int t = start;
    for (; t + 2 <= end; t += 2) {
        int s0 = adj[t], s1 = adj[t + 1];
        float w0 = dinv[s0], w1 = dinv[s1];
        float4 v0 = m4[(long long)s0 * 16 + l];
        float4 v1 = m4[(long long)s1 * 16 + l];
        a0.x += v0.x * w0; a0.y += v0.y * w0; a0.z += v0.z * w0; a0.w += v0.w * w0;
        a1.x += v1.x * w1; a1.y += v1.y * w1; a1.z += v1.z * w1; a1.w += v1.w * w1;
    }
    if (t < end) {
        int s = adj[t];
        float w = dinv[s];
        float4 v = m4[(long long)s * 16 + l];
        a0.x += v.x * w; a0.y += v.y * w; a0.z += v.z * w; a0.w += v.w * w;
    }
    float4 r;
    r.x = (a0.x + a1.x) * dv; r.y = (a0.y + a1.y) * dv;
    r.z = (a0.z + a1.z) * dv; r.w = (a0.w + a1.w) * dv;
    if (RELU) {
        r.x = fmaxf(r.x, 0.f); r.y = fmaxf(r.y, 0.f);
        r.z = fmaxf(r.z, 0.f); r.w = fmaxf(r.w, 0.f);
    }
    out4[(long long)d * 16 + l] = r;
}

// neighbor mean: out = (sum_{s in N(d)} h[s]) / max(deg,1)
__global__ __launch_bounds__(256) void gather_mean4(const float4* __restrict__ h4,
                                                    const int* __restrict__ rowStart,
                                                    const int* __restrict__ adj,
                                                    float4* __restrict__ out4, int N) {
    int gid = blockIdx.x * 256 + threadIdx.x;
    int d = gid >> 4;
    if (d >= N) return;
    int l = gid & 15;
    int start = rowStart[d], end = rowStart[d + 1];
    int deg = end - start;
    float4 a0, a1;
    a0.x = 0.f; a0.y = 0.f; a0.z = 0.f; a0.w = 0.f;
    a1 = a0;
    int t = start;
    for (; t + 2 <= end; t += 2) {
        int s0 = adj[t], s1 = adj[t + 1];
        float4 v0 = h4[(long long)s0 * 16 + l];
        float4 v1 = h4[(long long)s1 * 16 + l];
        a0.x += v0.x; a0.y += v0.y; a0.z += v0.z; a0.w += v0.w;
        a1.x += v1.x; a1.y += v1.y; a1.z += v1.z; a1.w += v1.w;
    }
    if (t < end) {
        float4 v = h4[(long long)adj[t] * 16 + l];
        a0.x += v.x; a0.y += v.y; a0.z += v.z; a0.w += v.w;
    }
    float inv = 1.0f / (float)max(deg, 1);
    float4 r;
    r.x = (a0.x + a1.x) * inv; r.y = (a0.y + a1.y) * inv;
    r.z = (a0.z + a1.z) * inv; r.w = (a0.w + a1.w) * inv;
    out4[(long long)d * 16 + l] = r;
}

// ---------------- fused 2-layer MLP: out = relu(In@Wa + ba) @ Wb + bb ----------------
__global__ __launch_bounds__(128) void mlp2_kernel(const float* __restrict__ In,
                                                   const float* __restrict__ Wa,
                                                   const float* __restrict__ ba,
                                                   const float* __restrict__ Wb,
                                                   const float* __restrict__ bb,
                                                   float* __restrict__ out, int N) {
    constexpr int R = 16;
    const int j = threadIdx.x;          // 0..127 (output col)
    const int row0 = blockIdx.x * R;
    __shared__ float ins[R][64];
    __shared__ float t[R][128];
    for (int idx = threadIdx.x; idx < R * 64; idx += 128) {
        int r = idx >> 6, k = idx & 63;
        int row = row0 + r;
        ins[r][k] = (row < N) ? In[(long long)row * 64 + k] : 0.0f;
    }
    __syncthreads();
    float acc[R];
    float b1 = ba[j];
#pragma unroll
    for (int r = 0; r < R; ++r) acc[r] = b1;
    for (int k = 0; k < 64; ++k) {
        float w = Wa[k * 128 + j];
#pragma unroll
        for (int r = 0; r < R; ++r) acc[r] += ins[r][k] * w;
    }
#pragma unroll
    for (int r = 0; r < R; ++r) t[r][j] = fmaxf(acc[r], 0.0f);
    __syncthreads();
    float b2 = bb[j];
#pragma unroll
    for (int r = 0; r < R; ++r) acc[r] = b2;
    for (int k = 0; k < 128; ++k) {
        float w = Wb[k * 128 + j];
#pragma unroll
        for (int r = 0; r < R; ++r) acc[r] += t[r][k] * w;
    }
#pragma unroll
    for (int r = 0; r < R; ++r) {
        int row = row0 + r;
        if (row < N) out[(long long)row * 128 + j] = acc[r];
    }
}

extern "C" void kernel_launch(void* const* d_in, const int* in_sizes, int n_in,
                              void* d_out, int out_size, void* d_ws, size_t ws_size,
                              hipStream_t stream) {
    const float* x   = (const float*)d_in[0];
    const int*   ei  = (const int*)  d_in[1];
    const float* W1  = (const float*)d_in[2];
    const float* W2  = (const float*)d_in[3];
    const float* Wx1 = (const float*)d_in[4];
    const float* bx1 = (const float*)d_in[5];
    const float* Wx2 = (const float*)d_in[6];
    const float* bx2 = (const float*)d_in[7];
    const float* Wh1 = (const float*)d_in[8];
    const float* bh1 = (const float*)d_in[9];
    const float* Wh2 = (const float*)d_in[10];
    const float* bh2 = (const float*)d_in[11];

    const int NFEAT = 128, NHID = 64;
    const int N = in_sizes[0] / NFEAT;       // 100000
    const int E = in_sizes[1] / 2;           // 1600000
    const int NBUCK = (N + BUCK_W - 1) >> BUCK_SHIFT;   // 782 (<=1024 required)

    float* out   = (float*)d_out;
    float* h_out = out;                          // [N,64]
    float* xhat  = out + (long long)N * NHID;    // [N,128]
    float* mhat  = xhat + (long long)N * NFEAT;  // [N,128]

    // workspace layout (8/16B-aligned chunks):
    //   adj[E] | rowStart[N+2 pad] | bucketCnt[1024] | bucketOff[1026 pad] |
    //   bucketCursor[1024] | dinv[N] | mbuf[N*64] (staging uint2[E] aliases here) | hbuf[N*64]
    char* wsb = (char*)d_ws;
    int*   adj       = (int*)wsb;        wsb += (size_t)E * 4;
    int*   rowStart  = (int*)wsb;        wsb += (size_t)(N + 2) * 4;
    int*   bucketCnt = (int*)wsb;        wsb += (size_t)MAXB * 4;
    int*   bucketOff = (int*)wsb;        wsb += (size_t)(MAXB + 2) * 4;
    int*   bucketCur = (int*)wsb;        wsb += (size_t)MAXB * 4;
    float* dinv      = (float*)wsb;      wsb += (size_t)N * 4;
    float* mbuf      = (float*)wsb;      wsb += (size_t)N * 64 * 4;
    float* hbuf      = (float*)wsb;
    uint2* staging   = (uint2*)mbuf;     // 12.8 MB, dead before mbuf's first write

    const int B = 256;
    const int gridN   = (N + B - 1) / B;
    const int gridG   = (N + 31) / 32;                    // gemm64 blocks
    const int gridMLP = (N + 15) / 16;                    // mlp2 blocks
    const int gridGa  = ((N * 16) + B - 1) / B;           // gather4 blocks
    const int gridEm  = (E + EMIT_CHUNK - 1) / EMIT_CHUNK;

    const int* srcp = ei;
    const int* dstp = ei + E;

    // ---- CSR build (two-level counting sort) ----
    hipMemsetAsync(bucketCnt, 0, (size_t)MAXB * 4, stream);
    bucket_count<<<256, 256, 0, stream>>>(dstp, bucketCnt, E, NBUCK);
    bucket_scan<<<1, 1024, 0, stream>>>(bucketCnt, bucketOff, bucketCur, NBUCK, E);
    bucket_emit<<<gridEm, 256, 0, stream>>>(srcp, dstp, bucketCur, staging, E, NBUCK);
    bucket_sort<<<NBUCK, 256, 0, stream>>>(staging, bucketOff, rowStart, adj, N, NBUCK, E);
    dinv_kernel<<<gridN, B, 0, stream>>>(rowStart, dinv, N);

    // ---- layer 1: m = x@W1 ; h1 = relu(gather_combine(m)) ----
    gemm64<128><<<gridG, B, 0, stream>>>(x, W1, mbuf, N);
    gather_combine4<1><<<gridGa, B, 0, stream>>>((const float4*)mbuf, rowStart, adj, dinv,
                                                 (float4*)hbuf, N);

    // ---- layer 2: m = h1@W2 ; h = gather_combine(m) -> d_out ----
    gemm64<64><<<gridG, B, 0, stream>>>(hbuf, W2, mbuf, N);
    gather_combine4<0><<<gridGa, B, 0, stream>>>((const float4*)mbuf, rowStart, adj, dinv,
                                                 (float4*)h_out, N);

    // ---- neighbor mean of h -> mbuf (reused) ----
    gather_mean4<<<gridGa, B, 0, stream>>>((const float4*)h_out, rowStart, adj,
                                           (float4*)mbuf, N);

    // ---- decoders ----
    mlp2_kernel<<<gridMLP, 128, 0, stream>>>(h_out, Wx1, bx1, Wx2, bx2, xhat, N);
    mlp2_kernel<<<gridMLP, 128, 0, stream>>>(mbuf, Wh1, bh1, Wh2, bh2, mhat, N);
}